// Round 16
// baseline (61.158 us; speedup 1.0000x reference)
//
#include <hip/hip_runtime.h>
#include <cmath>

// Problem constants
#define BB 4
#define NN 1024
#define DD 512
#define HH 8
#define HDIM 64
#define ROWS (BB * NN)      // 4096
#define NCHUNK 16
#define KA 512
#define WMAT ((size_t)512 * 512)    // one fp16 weight matrix, elems

typedef _Float16 f16;
typedef f16   f16x8 __attribute__((ext_vector_type(8)));
typedef f16   f16x4 __attribute__((ext_vector_type(4)));
typedef float f32x4 __attribute__((ext_vector_type(4)));

#define GLOAD_LDS16(g, l) \
    __builtin_amdgcn_global_load_lds((const __attribute__((address_space(1))) void*)(g), \
                                     (__attribute__((address_space(3))) void*)(l), 16, 0, 0)

// ---------------------------------------------------------------------------
// Fused split: x -> fp16 rows; W -> fp16. 768 blocks x 4 float4/thread.
// ---------------------------------------------------------------------------
__global__ __launch_bounds__(256)
void split_all(const float* __restrict__ x,
               const float* __restrict__ Wq, const float* __restrict__ Wk,
               const float* __restrict__ Wv, const float* __restrict__ Wo,
               f16* __restrict__ xa, f16* __restrict__ wa)
{
    for (int f4 = blockIdx.x * 256 + threadIdx.x; f4 < 786432; f4 += 768 * 256) {
        const float* src;
        f16* dstbase;
        int t;
        if (f4 < 524288) {                  // x: 512K float4
            t = f4;
            src = x;
            dstbase = xa;
        } else {                            // weights: 4 x 64K float4
            int w = f4 - 524288;
            int m = w >> 16;
            t = w & 65535;
            src = (m == 0) ? Wq : (m == 1) ? Wk : (m == 2) ? Wv : Wo;
            dstbase = wa + (size_t)m * WMAT;
        }
        float4 v = ((const float4*)src)[t];
        int r = t >> 7;
        int c = (t & 127) * 4;
        f16x4 h;
        h[0] = (f16)v.x; h[1] = (f16)v.y; h[2] = (f16)v.z; h[3] = (f16)v.w;
        *(f16x4*)(dstbase + (size_t)r * 512 + c) = h;
    }
}

// ---------------------------------------------------------------------------
// Projection GEMM body (r15-validated OUTMODE 0 logic, factored):
// 128x128 tile, BK=64, XOR-8 swizzle, dbuf LDS + counted vmcnt, K=512.
// z=0: elu+L2norm -> qf. z=1: elu+L2norm -> kf + ktb (LDS transpose).
// z=2: bias only -> vtb (LDS transpose). lds = 64KB (As 32KB | Bs 32KB).
// ---------------------------------------------------------------------------
__device__ __forceinline__
void proj_body(const f16* __restrict__ A, const f16* __restrict__ Wz,
               const float* __restrict__ bias, const int z,
               const int r0, const int cw,
               f16* __restrict__ qf, f16* __restrict__ kf,
               f16* __restrict__ ktb, f16* __restrict__ vtb,
               f16* lds)
{
    f16* As0 = lds;             // [2][8192]
    f16* Bs0 = lds + 16384;     // [2][8192]

    const int t    = threadIdx.x;
    const int lane = t & 63;
    const int wid  = t >> 6;
    const int wr   = wid >> 1;
    const int wc   = wid & 1;
    const int l16  = lane & 15;
    const int g16  = lane >> 4;

    auto stage = [&](int buf, int kt) {
        const int kb = kt * 64;
        #pragma unroll
        for (int i = 0; i < 4; ++i) {
            int f = i * 256 + t;
            int row = f >> 3;
            int sc  = (f & 7) ^ (row & 7);
            GLOAD_LDS16(A + (size_t)(r0 + row) * KA + kb + sc * 8, As0 + buf * 8192 + f * 8);
        }
        #pragma unroll
        for (int i = 0; i < 4; ++i) {
            int f = i * 256 + t;
            int row = f >> 3;
            int sc  = (f & 7) ^ (row & 7);
            GLOAD_LDS16(Wz + (size_t)(cw + row) * KA + kb + sc * 8, Bs0 + buf * 8192 + f * 8);
        }
    };

    f32x4 acc[4][4] = {};

    stage(0, 0);

    for (int kt = 0; kt < 8; ++kt) {
        const int buf = kt & 1;
        if (kt < 7) {
            stage(buf ^ 1, kt + 1);    // next tile's loads: stay in flight
            asm volatile("s_waitcnt vmcnt(8)" ::: "memory");
        } else {
            asm volatile("s_waitcnt vmcnt(0)" ::: "memory");
        }
        __builtin_amdgcn_s_barrier();
        __builtin_amdgcn_sched_barrier(0);

        #pragma unroll
        for (int kk = 0; kk < 2; ++kk) {
            f16x8 af[4], bfr[4];
            #pragma unroll
            for (int mi = 0; mi < 4; ++mi) {
                int lr = wr * 64 + mi * 16 + l16;
                int sc = (kk * 4 + g16) ^ (lr & 7);
                af[mi] = *(const f16x8*)(As0 + buf * 8192 + lr * 64 + sc * 8);
            }
            #pragma unroll
            for (int ni = 0; ni < 4; ++ni) {
                int lr = wc * 64 + ni * 16 + l16;
                int sc = (kk * 4 + g16) ^ (lr & 7);
                bfr[ni] = *(const f16x8*)(Bs0 + buf * 8192 + lr * 64 + sc * 8);
            }
            #pragma unroll
            for (int mi = 0; mi < 4; ++mi)
                #pragma unroll
                for (int ni = 0; ni < 4; ++ni)
                    acc[mi][ni] = __builtin_amdgcn_mfma_f32_16x16x32_f16(af[mi], bfr[ni], acc[mi][ni], 0, 0, 0);
        }
        __builtin_amdgcn_s_barrier();
    }

    // bias (+ elu for q,k)
    #pragma unroll
    for (int mi = 0; mi < 4; ++mi)
        #pragma unroll
        for (int ni = 0; ni < 4; ++ni) {
            float bv = bias[cw + wc * 64 + ni * 16 + l16];
            #pragma unroll
            for (int r = 0; r < 4; ++r) {
                float v = acc[mi][ni][r] + bv;
                if (z < 2) v = (v > 0.f) ? v : expm1f(v);
                acc[mi][ni][r] = v;
            }
        }
    if (z < 2) {
        // per-(row, head) L2 norm; wave's 64 cols == one head
        #pragma unroll
        for (int mi = 0; mi < 4; ++mi)
            #pragma unroll
            for (int r = 0; r < 4; ++r) {
                float ss = 0.f;
                #pragma unroll
                for (int ni = 0; ni < 4; ++ni) ss += acc[mi][ni][r] * acc[mi][ni][r];
                ss += __shfl_xor(ss, 1);
                ss += __shfl_xor(ss, 2);
                ss += __shfl_xor(ss, 4);
                ss += __shfl_xor(ss, 8);
                float sc = 1.f / fmaxf(sqrtf(ss), 1e-12f);
                #pragma unroll
                for (int ni = 0; ni < 4; ++ni) acc[mi][ni][r] *= sc;
            }
    }

    const int h = (cw >> 6) + wc;        // head of this wave's 64 cols
    const int b = r0 >> 10;              // all 128 rows same batch

    // direct fp16 [bh][n][d] store for q,k
    if (z <= 1) {
        f16* plane = (z == 0) ? qf : kf;
        #pragma unroll
        for (int mi = 0; mi < 4; ++mi)
            #pragma unroll
            for (int r = 0; r < 4; ++r) {
                int rg = r0 + wr * 64 + mi * 16 + g16 * 4 + r;
                f16* dst = plane + ((size_t)(b * HH + h) * NN + (rg & 1023)) * HDIM;
                #pragma unroll
                for (int ni = 0; ni < 4; ++ni) dst[ni * 16 + l16] = (f16)acc[mi][ni][r];
            }
    }

    // transposed fp16 [bh][d][n] store for k,v via per-wave LDS transpose
    if (z >= 1) {
        f16* tb = (z == 1) ? ktb : vtb;
        f16* T = (wid < 2) ? (As0 + wid * 4096) : (Bs0 + (wid - 2) * 4096);
        #pragma unroll
        for (int mi = 0; mi < 4; ++mi)
            #pragma unroll
            for (int ni = 0; ni < 4; ++ni)
                #pragma unroll
                for (int r = 0; r < 4; ++r) {
                    int n_ = mi * 16 + g16 * 4 + r;      // wave-local row
                    int d_ = ni * 16 + l16;              // wave-local col
                    *(f16*)((char*)T + d_ * 128 + (((n_ >> 3) ^ (d_ & 7)) * 16) + (n_ & 7) * 2)
                        = (f16)acc[mi][ni][r];
                }
        __syncthreads();
        const int n0 = (r0 & 1023) + wr * 64;
        #pragma unroll
        for (int p = 0; p < 8; ++p) {
            int d_ = p * 8 + (lane >> 3);
            int ck = lane & 7;
            f16x8 v8 = *(const f16x8*)((char*)T + d_ * 128 + ((ck ^ (d_ & 7)) * 16));
            *(f16x8*)(tb + ((size_t)(b * HH + h) * HDIM + d_) * NN + n0 + ck * 8) = v8;
        }
    }
}

// ---------------------------------------------------------------------------
// k,v projections: grid (256), z = 1 + (c0>>9).
// ---------------------------------------------------------------------------
__global__ __launch_bounds__(256)
void mm_kv(const f16* __restrict__ xa, const f16* __restrict__ wa,
           const float* __restrict__ bk, const float* __restrict__ bv,
           f16* __restrict__ kf, f16* __restrict__ ktb, f16* __restrict__ vtb)
{
    __shared__ __align__(16) f16 LB[32768];   // 64KB

    const int lin = blockIdx.x;
    const int swz = (lin & 7) * 32 + (lin >> 3);   // bijective on 256
    const int bx  = swz & 31;
    const int by  = swz >> 5;                      // 0..7

    const int r0 = bx * 128;
    const int c0 = by * 128;
    const int z  = 1 + (c0 >> 9);                  // 1 (k) or 2 (v)
    const int cw = c0 & 511;

    proj_body(xa, wa + (size_t)z * WMAT, (z == 1) ? bk : bv, z,
              r0, cw, nullptr, kf, ktb, vtb, LB);
}

// ---------------------------------------------------------------------------
// Concurrent q-projection (blocks 0..127) + state/prefix (blocks 128..255).
// Independent work: q needs xa/wa; state needs ktb/vtb (from mm_kv).
// ---------------------------------------------------------------------------
__global__ __launch_bounds__(256)
void q_and_state(const f16* __restrict__ xa, const f16* __restrict__ wa,
                 const float* __restrict__ bq,
                 const f16* __restrict__ ktb, const f16* __restrict__ vtb,
                 f16* __restrict__ qf, f16* __restrict__ ptb)
{
    __shared__ __align__(16) f16 LB[32768];   // 64KB

    const int t    = threadIdx.x;
    const int lane = t & 63;
    const int wid  = t >> 6;
    const int l16  = lane & 15;
    const int g16  = lane >> 4;

    if (blockIdx.x < 128) {
        // ---------------- q projection ----------------
        const int lin = blockIdx.x;
        const int swz = (lin & 7) * 16 + (lin >> 3);   // bijective on 128
        const int bx  = swz & 31;
        const int by  = swz >> 5;                      // 0..3
        proj_body(xa, wa, bq, 0, bx * 128, by * 128,
                  qf, nullptr, nullptr, nullptr, LB);
        return;
    }

    // ---------------- state + exclusive prefix (r15 state_prefix body) ----
    const int idx = blockIdx.x - 128;
    const int bh = idx >> 2;
    const int eq = idx & 3;          // e quarter: rows [eq*16, eq*16+16)

    f16* Kt0 = LB;                   // [2][4096]
    f16* Vt0 = LB + 8192;            // [2][4096]
    f16* PtL = LB + 16384;           // [1024]

    auto stage = [&](int ch, int buf) {
        #pragma unroll
        for (int i = 0; i < 2; ++i) {
            int f = i * 256 + t;
            int row = f >> 3;
            int sc  = (f & 7) ^ (row & 7);
            GLOAD_LDS16(ktb + ((size_t)bh * HDIM + row) * NN + ch * 64 + sc * 8, Kt0 + buf * 4096 + f * 8);
            GLOAD_LDS16(vtb + ((size_t)bh * HDIM + row) * NN + ch * 64 + sc * 8, Vt0 + buf * 4096 + f * 8);
        }
    };

    float pref[4] = {};
    const int d = wid * 16 + l16;    // this thread's d column

    stage(0, 0);

    for (int ch = 0; ch < NCHUNK; ++ch) {
        const int buf = ch & 1;
        stage(ch < 15 ? ch + 1 : 15, buf ^ 1);   // prefetch (clamped; dbuf)

        // write exclusive prefix (sum of chunks < ch) into PtL, swizzled
        #pragma unroll
        for (int r = 0; r < 4; ++r) {
            int e = g16 * 4 + r;     // local e row; (eq*16+e)&7 == e&7
            *(f16*)((char*)PtL + e * 128 + (((d >> 3) ^ (e & 7)) * 16) + (d & 7) * 2)
                = (f16)pref[r];
        }

        asm volatile("s_waitcnt vmcnt(4)" ::: "memory");   // current stage done
        asm volatile("s_waitcnt lgkmcnt(0)" ::: "memory"); // own PtL writes done
        __builtin_amdgcn_s_barrier();
        __builtin_amdgcn_sched_barrier(0);

        // coalesced copy PtL -> ptb quarter (image layout, gload-ready)
        {
            f16x4 v4 = *(const f16x4*)(PtL + t * 4);
            *(f16x4*)(ptb + (size_t)(bh * NCHUNK + ch) * 4096 + eq * 1024 + t * 4) = v4;
        }

        // S^T slice: A = vT rows (this quarter), B = kT rows (wave's d block)
        f32x4 sacc = {};
        #pragma unroll
        for (int ks = 0; ks < 2; ++ks) {
            int ra = eq * 16 + l16;
            f16x8 av = *(const f16x8*)(Vt0 + buf * 4096 + ra * 64 + ((ks * 4 + g16) ^ (ra & 7)) * 8);
            int rb = wid * 16 + l16;
            f16x8 bv = *(const f16x8*)(Kt0 + buf * 4096 + rb * 64 + ((ks * 4 + g16) ^ (rb & 7)) * 8);
            sacc = __builtin_amdgcn_mfma_f32_16x16x32_f16(av, bv, sacc, 0, 0, 0);
        }
        #pragma unroll
        for (int r = 0; r < 4; ++r) pref[r] += sacc[r];

        __builtin_amdgcn_s_barrier();    // PtL safe to rewrite next iter
    }
}

// ---------------------------------------------------------------------------
// Chunk attention via MFMA: scores = tril(Q K^T); O = Q P^T + scores V^T.
// Pt tile gloaded verbatim (pre-swizzled by state path). (r15-validated)
// ---------------------------------------------------------------------------
__global__ __launch_bounds__(256)
void attn_chunk(const f16* __restrict__ qf, const f16* __restrict__ kf,
                const f16* __restrict__ vtb, const f16* __restrict__ ptb,
                f16* __restrict__ aug)
{
    __shared__ __align__(16) f16 Qs[64 * 64];   // 8KB each, swizzled rows
    __shared__ __align__(16) f16 Ks[64 * 64];
    __shared__ __align__(16) f16 Vt[64 * 64];
    __shared__ __align__(16) f16 Pt[64 * 64];
    __shared__ __align__(16) f16 Ss[64 * 64];

    const int bh = blockIdx.x;
    const int ch = blockIdx.y;
    const int t  = threadIdx.x;
    const int lane = t & 63;
    const int wid  = t >> 6;
    const int wr   = wid >> 1;
    const int wc   = wid & 1;
    const int l16  = lane & 15;
    const int g16  = lane >> 4;

    // stage q, k (rows n), vT (rows e), Pt (identity copy, pre-swizzled)
    #pragma unroll
    for (int i = 0; i < 2; ++i) {
        int f = i * 256 + t;
        int row = f >> 3;
        int sc  = (f & 7) ^ (row & 7);
        GLOAD_LDS16(qf  + ((size_t)bh * NN + ch * 64 + row) * HDIM + sc * 8, Qs + f * 8);
        GLOAD_LDS16(kf  + ((size_t)bh * NN + ch * 64 + row) * HDIM + sc * 8, Ks + f * 8);
        GLOAD_LDS16(vtb + ((size_t)bh * HDIM + row) * NN + ch * 64 + sc * 8, Vt + f * 8);
        GLOAD_LDS16(ptb + (size_t)(bh * NCHUNK + ch) * 4096 + f * 8, Pt + f * 8);
    }
    __syncthreads();

    // scores = Q K^T (A=q rows i, B=k rows j), mask, -> Ss fp16
    f32x4 sacc[2][2] = {};
    #pragma unroll
    for (int ks = 0; ks < 2; ++ks) {
        f16x8 af[2], bfr[2];
        #pragma unroll
        for (int mi = 0; mi < 2; ++mi) {
            int row = wr * 32 + mi * 16 + l16;
            int sc  = (ks * 4 + g16) ^ (row & 7);
            af[mi] = *(const f16x8*)(Qs + row * 64 + sc * 8);
        }
        #pragma unroll
        for (int ni = 0; ni < 2; ++ni) {
            int row = wc * 32 + ni * 16 + l16;
            int sc  = (ks * 4 + g16) ^ (row & 7);
            bfr[ni] = *(const f16x8*)(Ks + row * 64 + sc * 8);
        }
        #pragma unroll
        for (int mi = 0; mi < 2; ++mi)
            #pragma unroll
            for (int ni = 0; ni < 2; ++ni)
                sacc[mi][ni] = __builtin_amdgcn_mfma_f32_16x16x32_f16(af[mi], bfr[ni], sacc[mi][ni], 0, 0, 0);
    }
    #pragma unroll
    for (int mi = 0; mi < 2; ++mi)
        #pragma unroll
        for (int ni = 0; ni < 2; ++ni)
            #pragma unroll
            for (int r = 0; r < 4; ++r) {
                int i = wr * 32 + mi * 16 + g16 * 4 + r;
                int j = wc * 32 + ni * 16 + l16;
                float v = (j <= i) ? sacc[mi][ni][r] : 0.f;
                *(f16*)((char*)Ss + i * 128 + (((j >> 3) ^ (i & 7)) * 16) + (j & 7) * 2) = (f16)v;
            }
    __syncthreads();

    // O = Q P^T + S V^T
    f32x4 oacc[2][2] = {};
    #pragma unroll
    for (int ks = 0; ks < 2; ++ks) {
        f16x8 af[2], bfr[2];
        #pragma unroll
        for (int mi = 0; mi < 2; ++mi) {
            int row = wr * 32 + mi * 16 + l16;
            int sc  = (ks * 4 + g16) ^ (row & 7);
            af[mi] = *(const f16x8*)(Qs + row * 64 + sc * 8);
        }
        #pragma unroll
        for (int ni = 0; ni < 2; ++ni) {
            int row = wc * 32 + ni * 16 + l16;          // e
            int sc  = (ks * 4 + g16) ^ (row & 7);
            bfr[ni] = *(const f16x8*)(Pt + row * 64 + sc * 8);
        }
        #pragma unroll
        for (int mi = 0; mi < 2; ++mi)
            #pragma unroll
            for (int ni = 0; ni < 2; ++ni)
                oacc[mi][ni] = __builtin_amdgcn_mfma_f32_16x16x32_f16(af[mi], bfr[ni], oacc[mi][ni], 0, 0, 0);
    }
    #pragma unroll
    for (int ks = 0; ks < 2; ++ks) {
        f16x8 af[2], bfr[2];
        #pragma unroll
        for (int mi = 0; mi < 2; ++mi) {
            int row = wr * 32 + mi * 16 + l16;          // i
            int sc  = (ks * 4 + g16) ^ (row & 7);
            af[mi] = *(const f16x8*)(Ss + row * 64 + sc * 8);
        }
        #pragma unroll
        for (int ni = 0; ni < 2; ++ni) {
            int row = wc * 32 + ni * 16 + l16;          // e
            int sc  = (ks * 4 + g16) ^ (row & 7);
            bfr[ni] = *(const f16x8*)(Vt + row * 64 + sc * 8);
        }
        #pragma unroll
        for (int mi = 0; mi < 2; ++mi)
            #pragma unroll
            for (int ni = 0; ni < 2; ++ni)
                oacc[mi][ni] = __builtin_amdgcn_mfma_f32_16x16x32_f16(af[mi], bfr[ni], oacc[mi][ni], 0, 0, 0);
    }

    // emit fp16 rows for the out-projection
    const int b = bh >> 3;
    const int h = bh & 7;
    #pragma unroll
    for (int mi = 0; mi < 2; ++mi)
        #pragma unroll
        for (int ni = 0; ni < 2; ++ni)
            #pragma unroll
            for (int r = 0; r < 4; ++r) {
                int i = wr * 32 + mi * 16 + g16 * 4 + r;
                int e = wc * 32 + ni * 16 + l16;
                aug[((size_t)(b * NN + ch * 64 + i)) * KA + h * HDIM + e] = (f16)oacc[mi][ni][r];
            }
}

// ---------------------------------------------------------------------------
// Out projection: 128x64 tile, dbuf + counted vmcnt, grid (32,8). (r15)
// ---------------------------------------------------------------------------
__global__ __launch_bounds__(256)
void mm_out(const f16* __restrict__ A, const f16* __restrict__ Wz,
            const float* __restrict__ bo, float* __restrict__ out)
{
    __shared__ __align__(16) f16 As[2][128 * 64];   // 2 x 16KB
    __shared__ __align__(16) f16 Bs[2][64 * 64];    // 2 x 8KB

    const int t    = threadIdx.x;
    const int lane = t & 63;
    const int wid  = t >> 6;
    const int wr   = wid >> 1;
    const int wc   = wid & 1;
    const int l16  = lane & 15;
    const int g16  = lane >> 4;

    const int nwg = 32 * gridDim.y;
    const int lin = blockIdx.y * 32 + blockIdx.x;
    const int swz = (lin & 7) * (nwg >> 3) + (lin >> 3);
    const int bx  = swz & 31;
    const int by  = swz >> 5;

    const int r0 = bx * 128;
    const int c0 = by * 64;

    auto stage = [&](int buf, int kt) {
        const int kb = kt * 64;
        #pragma unroll
        for (int i = 0; i < 4; ++i) {
            int f = i * 256 + t;
            int row = f >> 3;
            int sc  = (f & 7) ^ (row & 7);
            GLOAD_LDS16(A + (size_t)(r0 + row) * KA + kb + sc * 8, As[buf] + f * 8);
        }
        #pragma unroll
        for (int i = 0; i < 2; ++i) {
            int f = i * 256 + t;
            int row = f >> 3;
            int sc  = (f & 7) ^ (row & 7);
            GLOAD_LDS16(Wz + (size_t)(c0 + row) * KA + kb + sc * 8, Bs[buf] + f * 8);
        }
    };

    f32x4 acc[4][2] = {};

    stage(0, 0);

    for (int kt = 0; kt < 8; ++kt) {
        const int buf = kt & 1;
        if (kt < 7) {
            stage(buf ^ 1, kt + 1);
            asm volatile("s_waitcnt vmcnt(6)" ::: "memory");
        } else {
            asm volatile("s_waitcnt vmcnt(0)" ::: "memory");
        }
        __builtin_amdgcn_s_barrier();
        __builtin_amdgcn_sched_barrier(0);

        #pragma unroll
        for (int kk = 0; kk < 2; ++kk) {
            f16x8 af[4], bfr[2];
            #pragma unroll
            for (int mi = 0; mi < 4; ++mi) {
                int lr = wr * 64 + mi * 16 + l16;
                int sc = (kk * 4 + g16) ^ (lr & 7);
                af[mi] = *(const f16x8*)(As[buf] + lr * 64 + sc * 8);
            }
            #pragma unroll
            for (int ni = 0; ni < 2; ++ni) {
                int lr = wc * 32 + ni * 16 + l16;
                int sc = (kk * 4 + g16) ^ (lr & 7);
                bfr[ni] = *(const f16x8*)(Bs[buf] + lr * 64 + sc * 8);
            }
            #pragma unroll
            for (int mi = 0; mi < 4; ++mi)
                #pragma unroll
                for (int ni = 0; ni < 2; ++ni)
                    acc[mi][ni] = __builtin_amdgcn_mfma_f32_16x16x32_f16(af[mi], bfr[ni], acc[mi][ni], 0, 0, 0);
        }
        __builtin_amdgcn_s_barrier();
    }

    #pragma unroll
    for (int mi = 0; mi < 4; ++mi)
        #pragma unroll
        for (int ni = 0; ni < 2; ++ni) {
            int cg = c0 + wc * 32 + ni * 16 + l16;
            float bv = bo[cg];
            #pragma unroll
            for (int r = 0; r < 4; ++r) {
                int rg = r0 + wr * 64 + mi * 16 + g16 * 4 + r;
                out[(size_t)rg * DD + cg] = acc[mi][ni][r] + bv;
            }
        }
}

// ---------------------------------------------------------------------------
extern "C" void kernel_launch(void* const* d_in, const int* in_sizes, int n_in,
                              void* d_out, int out_size, void* d_ws, size_t ws_size,
                              hipStream_t stream)
{
    (void)in_sizes; (void)n_in; (void)out_size; (void)ws_size;

    const float* x  = (const float*)d_in[0];
    const float* Wq = (const float*)d_in[1];
    const float* Wk = (const float*)d_in[2];
    const float* Wv = (const float*)d_in[3];
    const float* Wo = (const float*)d_in[4];
    const float* bq = (const float*)d_in[5];
    const float* bk = (const float*)d_in[6];
    const float* bv = (const float*)d_in[7];
    const float* bo = (const float*)d_in[8];
    float* out = (float*)d_out;

    // ws: qf 4M | kf 4M | ktb 4M | vtb 4M | ptb 4M | xa 4M | aug 4M | wa 2M
    char* ws = (char*)d_ws;
    f16* qf  = (f16*)(ws);
    f16* kf  = (f16*)(ws + (size_t)4  * 1024 * 1024);
    f16* ktb = (f16*)(ws + (size_t)8  * 1024 * 1024);
    f16* vtb = (f16*)(ws + (size_t)12 * 1024 * 1024);
    f16* ptb = (f16*)(ws + (size_t)16 * 1024 * 1024);
    f16* xa  = (f16*)(ws + (size_t)20 * 1024 * 1024);
    f16* aug = (f16*)(ws + (size_t)24 * 1024 * 1024);
    f16* wa  = (f16*)(ws + (size_t)28 * 1024 * 1024);

    dim3 blk(256);

    split_all<<<dim3(768), blk, 0, stream>>>(x, Wq, Wk, Wv, Wo, xa, wa);

    // k,v projections first (state depends only on k,v)
    mm_kv<<<dim3(256), blk, 0, stream>>>(xa, wa, bk, bv, kf, ktb, vtb);

    // q projection runs CONCURRENTLY with the sequential state/prefix pass
    q_and_state<<<dim3(256), blk, 0, stream>>>(xa, wa, bq, ktb, vtb, qf, ptb);

    attn_chunk<<<dim3(32, NCHUNK), blk, 0, stream>>>(qf, kf, vtb, ptb, aug);

    // out projection: K = 512
    mm_out<<<dim3(32, 8), blk, 0, stream>>>(aug, wa + (size_t)3 * WMAT, bo, out);
}

// Round 17
// 55.927 us; speedup vs baseline: 1.0935x; 1.0935x over previous
//
#include <hip/hip_runtime.h>
#include <cmath>

// Problem constants
#define BB 4
#define NN 1024
#define DD 512
#define HH 8
#define HDIM 64
#define ROWS (BB * NN)      // 4096
#define NCHUNK 16
#define KA 512
#define WMAT ((size_t)512 * 512)    // one fp16 weight matrix, elems

typedef _Float16 f16;
typedef f16   f16x8 __attribute__((ext_vector_type(8)));
typedef f16   f16x4 __attribute__((ext_vector_type(4)));
typedef float f32x4 __attribute__((ext_vector_type(4)));

#define GLOAD_LDS16(g, l) \
    __builtin_amdgcn_global_load_lds((const __attribute__((address_space(1))) void*)(g), \
                                     (__attribute__((address_space(3))) void*)(l), 16, 0, 0)

// ---------------------------------------------------------------------------
// Fused split: x -> fp16 rows; W -> fp16. 768 blocks x 4 float4/thread.
// ---------------------------------------------------------------------------
__global__ __launch_bounds__(256)
void split_all(const float* __restrict__ x,
               const float* __restrict__ Wq, const float* __restrict__ Wk,
               const float* __restrict__ Wv, const float* __restrict__ Wo,
               f16* __restrict__ xa, f16* __restrict__ wa)
{
    for (int f4 = blockIdx.x * 256 + threadIdx.x; f4 < 786432; f4 += 768 * 256) {
        const float* src;
        f16* dstbase;
        int t;
        if (f4 < 524288) {                  // x: 512K float4
            t = f4;
            src = x;
            dstbase = xa;
        } else {                            // weights: 4 x 64K float4
            int w = f4 - 524288;
            int m = w >> 16;
            t = w & 65535;
            src = (m == 0) ? Wq : (m == 1) ? Wk : (m == 2) ? Wv : Wo;
            dstbase = wa + (size_t)m * WMAT;
        }
        float4 v = ((const float4*)src)[t];
        int r = t >> 7;
        int c = (t & 127) * 4;
        f16x4 h;
        h[0] = (f16)v.x; h[1] = (f16)v.y; h[2] = (f16)v.z; h[3] = (f16)v.w;
        *(f16x4*)(dstbase + (size_t)r * 512 + c) = h;
    }
}

// ---------------------------------------------------------------------------
// fp16 MFMA GEMM: 128xBN tile, BK=64, XOR-8 swizzle, double-buffered LDS with
// counted vmcnt. K = 512 -> 8 iters. (r11/r15-validated)
// OUTMODE 0: BN=128, grid (32,12): z = c0>>9 picks q/k/v.
// OUTMODE 1: BN=64, grid (32,8): bias + row-major f32 store to out.
// ---------------------------------------------------------------------------
template<int OUTMODE>
__global__ __launch_bounds__(256)
void mm_f16(const f16* __restrict__ A, const f16* __restrict__ Wm,
            const float* __restrict__ b0, const float* __restrict__ b1,
            const float* __restrict__ b2,
            f16* __restrict__ qf, f16* __restrict__ kf,
            f16* __restrict__ ktb, f16* __restrict__ vtb,
            float* __restrict__ obase)
{
    constexpr int BN = (OUTMODE == 0) ? 128 : 64;
    constexpr int NW = BN / 32;
    constexpr int BR = BN / 32;

    __shared__ __align__(16) f16 As[2][128 * 64];   // 2 x 16KB
    __shared__ __align__(16) f16 Bs[2][BN * 64];    // 2 x (16KB or 8KB)

    const int t    = threadIdx.x;
    const int lane = t & 63;
    const int wid  = t >> 6;
    const int wr   = wid >> 1;
    const int wc   = wid & 1;
    const int l16  = lane & 15;
    const int g16  = lane >> 4;

    // bijective XCD swizzle over the linearized grid
    const int nwg = 32 * gridDim.y;
    const int lin = blockIdx.y * 32 + blockIdx.x;
    const int swz = (lin & 7) * (nwg >> 3) + (lin >> 3);
    const int bx  = swz & 31;
    const int by  = swz >> 5;

    const int r0 = bx * 128;
    const int c0 = by * BN;
    const int z  = (OUTMODE == 0) ? (c0 >> 9) : 0;
    const int cw = (OUTMODE == 0) ? (c0 & 511) : c0;

    const f16* Wz = Wm + (size_t)z * WMAT;

    auto stage = [&](int buf, int kt) {
        const int kb = kt * 64;
        #pragma unroll
        for (int i = 0; i < 4; ++i) {
            int f = i * 256 + t;
            int row = f >> 3;
            int sc  = (f & 7) ^ (row & 7);
            GLOAD_LDS16(A + (size_t)(r0 + row) * KA + kb + sc * 8, As[buf] + f * 8);
        }
        #pragma unroll
        for (int i = 0; i < BR; ++i) {
            int f = i * 256 + t;
            int row = f >> 3;
            int sc  = (f & 7) ^ (row & 7);
            GLOAD_LDS16(Wz + (size_t)(cw + row) * KA + kb + sc * 8, Bs[buf] + f * 8);
        }
    };

    f32x4 acc[4][NW] = {};

    stage(0, 0);

    for (int kt = 0; kt < 8; ++kt) {
        const int buf = kt & 1;
        if (kt < 7) {
            stage(buf ^ 1, kt + 1);    // next tile's loads: stay in flight
            if (OUTMODE == 0) asm volatile("s_waitcnt vmcnt(8)" ::: "memory");
            else              asm volatile("s_waitcnt vmcnt(6)" ::: "memory");
        } else {
            asm volatile("s_waitcnt vmcnt(0)" ::: "memory");
        }
        __builtin_amdgcn_s_barrier();      // tile kt fully in LDS (all waves)
        __builtin_amdgcn_sched_barrier(0);

        #pragma unroll
        for (int kk = 0; kk < 2; ++kk) {
            f16x8 af[4], bfr[NW];
            #pragma unroll
            for (int mi = 0; mi < 4; ++mi) {
                int lr = wr * 64 + mi * 16 + l16;
                int sc = (kk * 4 + g16) ^ (lr & 7);
                af[mi] = *(const f16x8*)(As[buf] + lr * 64 + sc * 8);
            }
            #pragma unroll
            for (int ni = 0; ni < NW; ++ni) {
                int lr = wc * (BN / 2) + ni * 16 + l16;
                int sc = (kk * 4 + g16) ^ (lr & 7);
                bfr[ni] = *(const f16x8*)(Bs[buf] + lr * 64 + sc * 8);
            }
            #pragma unroll
            for (int mi = 0; mi < 4; ++mi)
                #pragma unroll
                for (int ni = 0; ni < NW; ++ni)
                    acc[mi][ni] = __builtin_amdgcn_mfma_f32_16x16x32_f16(af[mi], bfr[ni], acc[mi][ni], 0, 0, 0);
        }
        __builtin_amdgcn_s_barrier();      // buf safe to rewrite at kt+2
    }

    // ---- epilogue --------------------------------------------------------
    if (OUTMODE == 1) {
        #pragma unroll
        for (int mi = 0; mi < 4; ++mi)
            #pragma unroll
            for (int ni = 0; ni < NW; ++ni) {
                int cg = c0 + wc * (BN / 2) + ni * 16 + l16;
                float bv = b0[cg];
                #pragma unroll
                for (int r = 0; r < 4; ++r) {
                    int rg = r0 + wr * 64 + mi * 16 + g16 * 4 + r;
                    obase[(size_t)rg * DD + cg] = acc[mi][ni][r] + bv;
                }
            }
    } else {
        const float* bias = (z == 0) ? b0 : (z == 1) ? b1 : b2;

        // bias (+ elu for q,k)
        #pragma unroll
        for (int mi = 0; mi < 4; ++mi)
            #pragma unroll
            for (int ni = 0; ni < NW; ++ni) {
                float bv = bias[cw + wc * 64 + ni * 16 + l16];
                #pragma unroll
                for (int r = 0; r < 4; ++r) {
                    float v = acc[mi][ni][r] + bv;
                    if (z < 2) v = (v > 0.f) ? v : expm1f(v);
                    acc[mi][ni][r] = v;
                }
            }
        if (z < 2) {
            // per-(row, head) L2 norm; wave's 64 cols == one head
            #pragma unroll
            for (int mi = 0; mi < 4; ++mi)
                #pragma unroll
                for (int r = 0; r < 4; ++r) {
                    float ss = 0.f;
                    #pragma unroll
                    for (int ni = 0; ni < NW; ++ni) ss += acc[mi][ni][r] * acc[mi][ni][r];
                    ss += __shfl_xor(ss, 1);
                    ss += __shfl_xor(ss, 2);
                    ss += __shfl_xor(ss, 4);
                    ss += __shfl_xor(ss, 8);
                    float sc = 1.f / fmaxf(sqrtf(ss), 1e-12f);
                    #pragma unroll
                    for (int ni = 0; ni < NW; ++ni) acc[mi][ni][r] *= sc;
                }
        }

        const int h = (cw >> 6) + wc;        // head of this wave's 64 cols
        const int b = r0 >> 10;              // all 128 rows same batch

        // direct fp16 [bh][n][d] store for q,k
        if (z <= 1) {
            f16* plane = (z == 0) ? qf : kf;
            #pragma unroll
            for (int mi = 0; mi < 4; ++mi)
                #pragma unroll
                for (int r = 0; r < 4; ++r) {
                    int rg = r0 + wr * 64 + mi * 16 + g16 * 4 + r;
                    f16* dst = plane + ((size_t)(b * HH + h) * NN + (rg & 1023)) * HDIM;
                    #pragma unroll
                    for (int ni = 0; ni < NW; ++ni) dst[ni * 16 + l16] = (f16)acc[mi][ni][r];
                }
        }

        // transposed fp16 [bh][d][n] store for k,v via per-wave LDS transpose
        if (z >= 1) {
            f16* tb = (z == 1) ? ktb : vtb;
            f16* T = (wid < 2) ? (As[0] + wid * 4096) : (Bs[0] + (wid - 2) * 4096);
            #pragma unroll
            for (int mi = 0; mi < 4; ++mi)
                #pragma unroll
                for (int ni = 0; ni < NW; ++ni)
                    #pragma unroll
                    for (int r = 0; r < 4; ++r) {
                        int n_ = mi * 16 + g16 * 4 + r;      // wave-local row
                        int d_ = ni * 16 + l16;              // wave-local col
                        *(f16*)((char*)T + d_ * 128 + (((n_ >> 3) ^ (d_ & 7)) * 16) + (n_ & 7) * 2)
                            = (f16)acc[mi][ni][r];
                    }
            __syncthreads();
            const int n0 = (r0 & 1023) + wr * 64;
            #pragma unroll
            for (int p = 0; p < 8; ++p) {
                int d_ = p * 8 + (lane >> 3);
                int ck = lane & 7;
                f16x8 v8 = *(const f16x8*)((char*)T + d_ * 128 + ((ck ^ (d_ & 7)) * 16));
                *(f16x8*)(tb + ((size_t)(b * HH + h) * HDIM + d_) * NN + n0 + ck * 8) = v8;
            }
        }
    }
}

// ---------------------------------------------------------------------------
// Sequential per-(bh, e-quarter) state + exclusive prefix. Emits Pt tiles
// fp16 in the swizzled-LDS-image layout so attn can gload them verbatim.
// Double-buffered kT/vT staging with counted vmcnt(4) (4 gload instr/stage).
// ---------------------------------------------------------------------------
__global__ __launch_bounds__(256)
void state_prefix(const f16* __restrict__ ktb, const f16* __restrict__ vtb,
                  f16* __restrict__ ptb)
{
    __shared__ __align__(16) f16 Kt[2][64 * 64];   // 8KB each, swizzled rows d
    __shared__ __align__(16) f16 Vt[2][64 * 64];   // 8KB each, swizzled rows e
    __shared__ __align__(16) f16 PtL[16 * 64];     // 2KB exclusive-prefix slice

    const int bh = blockIdx.x;
    const int eq = blockIdx.y;       // e quarter: rows [eq*16, eq*16+16)
    const int t  = threadIdx.x;
    const int lane = t & 63;
    const int wid  = t >> 6;
    const int l16  = lane & 15;
    const int g16  = lane >> 4;

    auto stage = [&](int ch, int buf) {
        #pragma unroll
        for (int i = 0; i < 2; ++i) {
            int f = i * 256 + t;
            int row = f >> 3;
            int sc  = (f & 7) ^ (row & 7);
            GLOAD_LDS16(ktb + ((size_t)bh * HDIM + row) * NN + ch * 64 + sc * 8, Kt[buf] + f * 8);
            GLOAD_LDS16(vtb + ((size_t)bh * HDIM + row) * NN + ch * 64 + sc * 8, Vt[buf] + f * 8);
        }
    };

    float pref[4] = {};
    const int d = wid * 16 + l16;    // this thread's d column

    stage(0, 0);

    for (int ch = 0; ch < NCHUNK; ++ch) {
        const int buf = ch & 1;
        stage(ch < 15 ? ch + 1 : 15, buf ^ 1);   // prefetch (clamped; dbuf)

        // write exclusive prefix (sum of chunks < ch) into PtL, swizzled
        #pragma unroll
        for (int r = 0; r < 4; ++r) {
            int e = g16 * 4 + r;     // local e row; (eq*16+e)&7 == e&7
            *(f16*)((char*)PtL + e * 128 + (((d >> 3) ^ (e & 7)) * 16) + (d & 7) * 2)
                = (f16)pref[r];
        }

        asm volatile("s_waitcnt vmcnt(4)" ::: "memory");   // current stage done
        asm volatile("s_waitcnt lgkmcnt(0)" ::: "memory"); // own PtL writes done
        __builtin_amdgcn_s_barrier();
        __builtin_amdgcn_sched_barrier(0);

        // coalesced copy PtL -> ptb quarter (image layout, gload-ready)
        {
            f16x4 v4 = *(const f16x4*)(PtL + t * 4);
            *(f16x4*)(ptb + (size_t)(bh * NCHUNK + ch) * 4096 + eq * 1024 + t * 4) = v4;
        }

        // S^T slice: A = vT rows (this quarter), B = kT rows (wave's d block)
        f32x4 sacc = {};
        #pragma unroll
        for (int ks = 0; ks < 2; ++ks) {
            int ra = eq * 16 + l16;
            f16x8 av = *(const f16x8*)(Vt[buf] + ra * 64 + ((ks * 4 + g16) ^ (ra & 7)) * 8);
            int rb = wid * 16 + l16;
            f16x8 bv = *(const f16x8*)(Kt[buf] + rb * 64 + ((ks * 4 + g16) ^ (rb & 7)) * 8);
            sacc = __builtin_amdgcn_mfma_f32_16x16x32_f16(av, bv, sacc, 0, 0, 0);
        }
        #pragma unroll
        for (int r = 0; r < 4; ++r) pref[r] += sacc[r];

        __builtin_amdgcn_s_barrier();    // PtL safe to rewrite next iter
    }
}

// ---------------------------------------------------------------------------
// Chunk attention via MFMA: scores = tril(Q K^T); O = Q P^T + scores V^T.
// Pt tile gloaded verbatim (pre-swizzled by state_prefix).
// ---------------------------------------------------------------------------
__global__ __launch_bounds__(256)
void attn_chunk(const f16* __restrict__ qf, const f16* __restrict__ kf,
                const f16* __restrict__ vtb, const f16* __restrict__ ptb,
                f16* __restrict__ aug)
{
    __shared__ __align__(16) f16 Qs[64 * 64];   // 8KB each, swizzled rows
    __shared__ __align__(16) f16 Ks[64 * 64];
    __shared__ __align__(16) f16 Vt[64 * 64];
    __shared__ __align__(16) f16 Pt[64 * 64];
    __shared__ __align__(16) f16 Ss[64 * 64];

    const int bh = blockIdx.x;
    const int ch = blockIdx.y;
    const int t  = threadIdx.x;
    const int lane = t & 63;
    const int wid  = t >> 6;
    const int wr   = wid >> 1;
    const int wc   = wid & 1;
    const int l16  = lane & 15;
    const int g16  = lane >> 4;

    // stage q, k (rows n), vT (rows e), Pt (identity copy, pre-swizzled)
    #pragma unroll
    for (int i = 0; i < 2; ++i) {
        int f = i * 256 + t;
        int row = f >> 3;
        int sc  = (f & 7) ^ (row & 7);
        GLOAD_LDS16(qf  + ((size_t)bh * NN + ch * 64 + row) * HDIM + sc * 8, Qs + f * 8);
        GLOAD_LDS16(kf  + ((size_t)bh * NN + ch * 64 + row) * HDIM + sc * 8, Ks + f * 8);
        GLOAD_LDS16(vtb + ((size_t)bh * HDIM + row) * NN + ch * 64 + sc * 8, Vt + f * 8);
        GLOAD_LDS16(ptb + (size_t)(bh * NCHUNK + ch) * 4096 + f * 8, Pt + f * 8);
    }
    __syncthreads();

    // scores = Q K^T (A=q rows i, B=k rows j), mask, -> Ss fp16
    f32x4 sacc[2][2] = {};
    #pragma unroll
    for (int ks = 0; ks < 2; ++ks) {
        f16x8 af[2], bfr[2];
        #pragma unroll
        for (int mi = 0; mi < 2; ++mi) {
            int row = wr * 32 + mi * 16 + l16;
            int sc  = (ks * 4 + g16) ^ (row & 7);
            af[mi] = *(const f16x8*)(Qs + row * 64 + sc * 8);
        }
        #pragma unroll
        for (int ni = 0; ni < 2; ++ni) {
            int row = wc * 32 + ni * 16 + l16;
            int sc  = (ks * 4 + g16) ^ (row & 7);
            bfr[ni] = *(const f16x8*)(Ks + row * 64 + sc * 8);
        }
        #pragma unroll
        for (int mi = 0; mi < 2; ++mi)
            #pragma unroll
            for (int ni = 0; ni < 2; ++ni)
                sacc[mi][ni] = __builtin_amdgcn_mfma_f32_16x16x32_f16(af[mi], bfr[ni], sacc[mi][ni], 0, 0, 0);
    }
    #pragma unroll
    for (int mi = 0; mi < 2; ++mi)
        #pragma unroll
        for (int ni = 0; ni < 2; ++ni)
            #pragma unroll
            for (int r = 0; r < 4; ++r) {
                int i = wr * 32 + mi * 16 + g16 * 4 + r;
                int j = wc * 32 + ni * 16 + l16;
                float v = (j <= i) ? sacc[mi][ni][r] : 0.f;
                *(f16*)((char*)Ss + i * 128 + (((j >> 3) ^ (i & 7)) * 16) + (j & 7) * 2) = (f16)v;
            }
    __syncthreads();

    // O = Q P^T + S V^T
    f32x4 oacc[2][2] = {};
    #pragma unroll
    for (int ks = 0; ks < 2; ++ks) {
        f16x8 af[2], bfr[2];
        #pragma unroll
        for (int mi = 0; mi < 2; ++mi) {
            int row = wr * 32 + mi * 16 + l16;
            int sc  = (ks * 4 + g16) ^ (row & 7);
            af[mi] = *(const f16x8*)(Qs + row * 64 + sc * 8);
        }
        #pragma unroll
        for (int ni = 0; ni < 2; ++ni) {
            int row = wc * 32 + ni * 16 + l16;          // e
            int sc  = (ks * 4 + g16) ^ (row & 7);
            bfr[ni] = *(const f16x8*)(Pt + row * 64 + sc * 8);
        }
        #pragma unroll
        for (int mi = 0; mi < 2; ++mi)
            #pragma unroll
            for (int ni = 0; ni < 2; ++ni)
                oacc[mi][ni] = __builtin_amdgcn_mfma_f32_16x16x32_f16(af[mi], bfr[ni], oacc[mi][ni], 0, 0, 0);
    }
    #pragma unroll
    for (int ks = 0; ks < 2; ++ks) {
        f16x8 af[2], bfr[2];
        #pragma unroll
        for (int mi = 0; mi < 2; ++mi) {
            int row = wr * 32 + mi * 16 + l16;          // i
            int sc  = (ks * 4 + g16) ^ (row & 7);
            af[mi] = *(const f16x8*)(Ss + row * 64 + sc * 8);
        }
        #pragma unroll
        for (int ni = 0; ni < 2; ++ni) {
            int row = wc * 32 + ni * 16 + l16;          // e
            int sc  = (ks * 4 + g16) ^ (row & 7);
            bfr[ni] = *(const f16x8*)(Vt + row * 64 + sc * 8);
        }
        #pragma unroll
        for (int mi = 0; mi < 2; ++mi)
            #pragma unroll
            for (int ni = 0; ni < 2; ++ni)
                oacc[mi][ni] = __builtin_amdgcn_mfma_f32_16x16x32_f16(af[mi], bfr[ni], oacc[mi][ni], 0, 0, 0);
    }

    // emit fp16 rows for the out-projection
    const int b = bh >> 3;
    const int h = bh & 7;
    #pragma unroll
    for (int mi = 0; mi < 2; ++mi)
        #pragma unroll
        for (int ni = 0; ni < 2; ++ni)
            #pragma unroll
            for (int r = 0; r < 4; ++r) {
                int i = wr * 32 + mi * 16 + g16 * 4 + r;
                int e = wc * 32 + ni * 16 + l16;
                aug[((size_t)(b * NN + ch * 64 + i)) * KA + h * HDIM + e] = (f16)oacc[mi][ni][r];
            }
}

// ---------------------------------------------------------------------------
extern "C" void kernel_launch(void* const* d_in, const int* in_sizes, int n_in,
                              void* d_out, int out_size, void* d_ws, size_t ws_size,
                              hipStream_t stream)
{
    (void)in_sizes; (void)n_in; (void)out_size; (void)ws_size;

    const float* x  = (const float*)d_in[0];
    const float* Wq = (const float*)d_in[1];
    const float* Wk = (const float*)d_in[2];
    const float* Wv = (const float*)d_in[3];
    const float* Wo = (const float*)d_in[4];
    const float* bq = (const float*)d_in[5];
    const float* bk = (const float*)d_in[6];
    const float* bv = (const float*)d_in[7];
    const float* bo = (const float*)d_in[8];
    float* out = (float*)d_out;

    // ws: qf 4M | kf 4M | ktb 4M | vtb 4M | ptb 4M | xa 4M | aug 4M | wa 2M
    char* ws = (char*)d_ws;
    f16* qf  = (f16*)(ws);
    f16* kf  = (f16*)(ws + (size_t)4  * 1024 * 1024);
    f16* ktb = (f16*)(ws + (size_t)8  * 1024 * 1024);
    f16* vtb = (f16*)(ws + (size_t)12 * 1024 * 1024);
    f16* ptb = (f16*)(ws + (size_t)16 * 1024 * 1024);
    f16* xa  = (f16*)(ws + (size_t)20 * 1024 * 1024);
    f16* aug = (f16*)(ws + (size_t)24 * 1024 * 1024);
    f16* wa  = (f16*)(ws + (size_t)28 * 1024 * 1024);

    dim3 blk(256);

    split_all<<<dim3(768), blk, 0, stream>>>(x, Wq, Wk, Wv, Wo, xa, wa);

    // fused q,k,v projections: N = 1536 (3 matrices x 512), K = 512
    mm_f16<0><<<dim3(32, 12), blk, 0, stream>>>(xa, wa, bq, bk, bv, qf, kf, ktb, vtb, nullptr);

    state_prefix<<<dim3(32, 4), blk, 0, stream>>>(ktb, vtb, ptb);
    attn_chunk<<<dim3(32, NCHUNK), blk, 0, stream>>>(qf, kf, vtb, ptb, aug);

    // out projection: K = 512
    mm_f16<1><<<dim3(32, 8), blk, 0, stream>>>(aug, wa + (size_t)3 * WMAT, bo, nullptr, nullptr,
                                               nullptr, nullptr, nullptr, nullptr, out);
}